// Round 1
// 95.118 us; speedup vs baseline: 1.0314x; 1.0314x over previous
//
#include <hip/hip_runtime.h>
#include <math.h>

#define H_IMG 1024
#define W_IMG 1280
#define NPIX (H_IMG * W_IMG)
#define TPB 256
#define PXPT 4   // pixels per thread; W_IMG % PXPT == 0 so a group never crosses a row

// ---------------------------------------------------------------------------
// Key insight (carried over): reference's jnp.linalg.pinv(J) uses
// rcond = 10*max(M,N)*eps ~= 1.56 > 1, so pinv(J) == 0, x0 == 0, R stays I.
// Outputs: R = I; warped = warp(ref, inv(K @ inv(K))); res = mask*(warped-target).
//
// New this round: Hm = K@inv(K) has structure [[a,0,c],[0,e,g],[0,0,1]], so the
// adjugate inverse has h1=h3=h6=h7=0 and h8 = det/det = 1.0 EXACTLY (IEEE x/x==1).
// Hence den == 1.0f and xs = h0*u + h2, ys = h4*v + h5 — bit-identical to the
// previous kernel's generic (h0*u + h1*v + h2)/den path, with no divides.
// ys/wy/y0 are per-row constants, hoisted per 4-pixel group.
// ---------------------------------------------------------------------------

__device__ __forceinline__ float tap(const float* __restrict__ img, int yi, int xi, float wt) {
    bool valid = (xi >= 0) & (xi < W_IMG) & (yi >= 0) & (yi < H_IMG);
    int yc = min(max(yi, 0), H_IMG - 1);
    int xc = min(max(xi, 0), W_IMG - 1);
    float v = img[yc * W_IMG + xc];
    return valid ? v * wt : 0.0f;
}

__global__ __launch_bounds__(TPB) void k_all(const float* __restrict__ ref,
                                             const float* __restrict__ target,
                                             const float* __restrict__ mask,
                                             const float* __restrict__ K,
                                             float* __restrict__ outR,
                                             float* __restrict__ out_res,
                                             float* __restrict__ out_warp) {
    int gid = blockIdx.x * TPB + threadIdx.x;
    int p0  = gid * PXPT;

    // ---- uniform homography coefficients (R = I), double adjugate as before ----
    float f  = K[0], cu = K[2];
    float f2 = K[4], cv = K[5];
    float Ki00 = 1.0f / f,  Ki02 = -cu / f;
    float Ki11 = 1.0f / f2, Ki12 = -cv / f2;
    float Hm0 = f * Ki00;            // a
    float Hm2 = f * Ki02 + cu;       // c
    float Hm4 = f2 * Ki11;           // e
    float Hm5 = f2 * Ki12 + cv;      // g
    double A = Hm0, C = Hm2, E = Hm4, G = Hm5;
    double invdet = 1.0 / (A * E);
    // identical expressions to the generic adjugate with the known zeros folded in:
    float h0 = (float)(E * invdet);                  // C00*inv
    float h2 = (float)((0.0 * G - C * E) * invdet);  // C20*inv = (b*g - c*e)*inv
    float h4 = (float)(A * invdet);                  // C11*inv
    float h5 = (float)(-(A * G - C * 0.0) * invdet); // C21*inv = -(a*g - c*d)*inv
    // h1 = h3 = h6 = h7 = 0, h8 = 1.0f exactly -> den == 1.0f, divides elided.

    int row  = p0 / W_IMG;           // constant-divisor -> mul_hi
    int col0 = p0 - row * W_IMG;

    // per-row warp coords (hoisted)
    float ys  = h4 * (float)row + h5;
    float y0f = floorf(ys);
    float wy  = ys - y0f;
    int   y0  = (int)y0f;
    bool  yok = (y0 >= 0) & (y0 + 1 < H_IMG);

    // vector loads (target/mask bases are buffer starts -> 16B aligned at p0)
    float4 tg4 = *reinterpret_cast<const float4*>(target + p0);
    float4 mk4 = *reinterpret_cast<const float4*>(mask + p0);
    float tg[4] = {tg4.x, tg4.y, tg4.z, tg4.w};
    float mk[4] = {mk4.x, mk4.y, mk4.z, mk4.w};

    float wv[4];
#pragma unroll
    for (int i = 0; i < PXPT; ++i) {
        float xs  = h0 * (float)(col0 + i) + h2;
        float x0f = floorf(xs);
        float wx  = xs - x0f;
        int   x0  = (int)x0f;
        float w00 = (1.f - wx) * (1.f - wy);
        float w01 = wx * (1.f - wy);
        float w10 = (1.f - wx) * wy;
        float w11 = wx * wy;
        bool fast = yok & (x0 >= 0) & (x0 + 1 < W_IMG);
        float acc;
        if (fast) {
            const float* r0 = ref + y0 * W_IMG + x0;
            const float* r1 = r0 + W_IMG;
            acc = r0[0] * w00 + r0[1] * w01 + r1[0] * w10 + r1[1] * w11;
        } else {
            acc = tap(ref, y0,     x0,     w00)
                + tap(ref, y0,     x0 + 1, w01)
                + tap(ref, y0 + 1, x0,     w10)
                + tap(ref, y0 + 1, x0 + 1, w11);
        }
        wv[i] = acc;
    }

    // scalar stores (out_res/out_warp start at +9 floats -> not 16B-alignable;
    // consecutive lanes still give fully-coalesced 256B/wave stores)
#pragma unroll
    for (int i = 0; i < PXPT; ++i) {
        out_warp[p0 + i] = wv[i];
        out_res[p0 + i]  = mk[i] * (wv[i] - tg[i]);
    }

    if (gid < 9) {
        outR[gid] = ((gid & 3) == 0) ? 1.0f : 0.0f;  // identity
    }
}

extern "C" void kernel_launch(void* const* d_in, const int* in_sizes, int n_in,
                              void* d_out, int out_size, void* d_ws, size_t ws_size,
                              hipStream_t stream) {
    const float* ref_img = (const float*)d_in[0];
    const float* target  = (const float*)d_in[1];
    const float* mask    = (const float*)d_in[2];
    const float* K       = (const float*)d_in[3];
    // d_in[4] (batch_proj_jac) unused: pinv cutoff makes x0 == 0 identically.

    float* out      = (float*)d_out;
    float* out_R    = out;             // 9
    float* out_res  = out + 9;         // NPIX
    float* out_warp = out + 9 + NPIX;  // NPIX

    k_all<<<NPIX / (TPB * PXPT), TPB, 0, stream>>>(ref_img, target, mask, K,
                                                   out_R, out_res, out_warp);
}